// Round 1
// 759.789 us; speedup vs baseline: 1.0566x; 1.0566x over previous
//
#include <hip/hip_runtime.h>

#define DIM 384
#define C4PER 96    // 384/4 float4s per row
// cols [0,256) = incoming mean (keyed by lg[2e+1]) -> 64 float4s
// cols [256,384) = outgoing mean (keyed by lg[2e]) -> 32 float4s

#define SCAN_BLOCK 256
#define SCAN_ITEMS 8
#define SCAN_CHUNK (SCAN_BLOCK * SCAN_ITEMS)  // 2048

// Per-edge: resolve global node ids, bump degree counts, RECORD RANKS.
// cnt[0..TN)   = in-degree  (keyed by lg[2e+1]+off) -> serves cols [0,256)
// cnt[TN..2TN) = out-degree (keyed by lg[2e]+off)   -> serves cols [256,384)
// rk[e] = (out-rank, in-rank): each edge's slot within its node's segment.
__global__ void count_kernel(const int* __restrict__ org, const int* __restrict__ ptr,
                             const int2* __restrict__ lg2, int B, int E, int TN,
                             int* __restrict__ cnt, int2* __restrict__ rk) {
    int e = blockIdx.x * blockDim.x + threadIdx.x;
    if (e >= E) return;
    int off = 0;
    for (int j = 0; j < B; ++j)
        if (e >= ptr[j + 1]) off += org[j];   // uniform addrs -> broadcast loads
    int2 nn = lg2[e];                          // (n_out, n_in), one dwordx2 load
    int n_out = nn.x + off;
    int n_in  = nn.y + off;
    int r_in  = atomicAdd(&cnt[n_in], 1);
    int r_out = atomicAdd(&cnt[TN + n_out], 1);
    rk[e] = make_int2(r_out, r_in);
}

// Exclusive scan, stage 1: per-block (2048 elems) partial scan + block sums.
__global__ void scan1_kernel(const int* __restrict__ cnt, int* __restrict__ offs,
                             int* __restrict__ bsum, int n) {
    __shared__ int s[SCAN_BLOCK];
    int base = blockIdx.x * SCAN_CHUNK;
    int tid = threadIdx.x;
    int v[SCAN_ITEMS];
    int tsum = 0;
#pragma unroll
    for (int j = 0; j < SCAN_ITEMS; ++j) {
        int i = base + tid * SCAN_ITEMS + j;
        v[j] = (i < n) ? cnt[i] : 0;
        tsum += v[j];
    }
    s[tid] = tsum;
    __syncthreads();
    for (int d = 1; d < SCAN_BLOCK; d <<= 1) {
        int t = (tid >= d) ? s[tid - d] : 0;
        __syncthreads();
        s[tid] += t;
        __syncthreads();
    }
    if (tid == SCAN_BLOCK - 1) bsum[blockIdx.x] = s[SCAN_BLOCK - 1];
    int run = (tid > 0) ? s[tid - 1] : 0;
#pragma unroll
    for (int j = 0; j < SCAN_ITEMS; ++j) {
        int i = base + tid * SCAN_ITEMS + j;
        if (i < n) offs[i] = run;
        run += v[j];
    }
}

// Stage 2: exclusive scan of block sums in place (single block).
__global__ void scan2_kernel(int* __restrict__ bsum, int nb) {
    __shared__ int s[SCAN_BLOCK];
    int tid = threadIdx.x;
    int carry = 0;
    for (int base = 0; base < nb; base += SCAN_BLOCK) {
        int i = base + tid;
        s[tid] = (i < nb) ? bsum[i] : 0;
        __syncthreads();
        for (int d = 1; d < SCAN_BLOCK; d <<= 1) {
            int t = (tid >= d) ? s[tid - d] : 0;
            __syncthreads();
            s[tid] += t;
            __syncthreads();
        }
        int excl = carry + ((tid > 0) ? s[tid - 1] : 0);
        if (i < nb) bsum[i] = excl;
        carry += s[SCAN_BLOCK - 1];
        __syncthreads();
    }
}

// Stage 3: add scanned block sums back.
__global__ void scan3_kernel(int* __restrict__ offs, const int* __restrict__ bsum, int n) {
    int i = blockIdx.x * blockDim.x + threadIdx.x;
    if (i < n) offs[i] += bsum[i / SCAN_CHUNK];
}

// Fill CSR edge lists using precomputed ranks — NO atomics, offs stays pristine.
__global__ void fill_kernel(const int* __restrict__ org, const int* __restrict__ ptr,
                            const int2* __restrict__ lg2, const int2* __restrict__ rk,
                            const int* __restrict__ offs, int B, int E, int TN,
                            int* __restrict__ list) {
    int e = blockIdx.x * blockDim.x + threadIdx.x;
    if (e >= E) return;
    int off = 0;
    for (int j = 0; j < B; ++j)
        if (e >= ptr[j + 1]) off += org[j];
    int2 nn = lg2[e];
    int2 r  = rk[e];
    list[offs[nn.y + off] + r.y] = e;        // in-list slot
    list[offs[TN + nn.x + off] + r.x] = e;   // out-list slot
}

// Gather-mean, divergence-free wave mapping:
//   threads [0, TN*64): in-half, node = i>>6, c4 = i&63  -> one wave == one node,
//     uniform slot & trip count, each x4 load = one contiguous 1 KB transaction.
//   threads [TN*64, TN*96): out-half, node = j>>5, c4 = 64+(j&31) -> 2 nodes/wave.
// TN*64 is a multiple of 256, so no wave mixes halves.
__global__ __launch_bounds__(256, 8)
void gather_kernel(const float4* __restrict__ x4,
                   const int* __restrict__ cnt, const int* __restrict__ offs,
                   const int* __restrict__ list,
                   float4* __restrict__ out4, int TN) {
    int i = blockIdx.x * blockDim.x + threadIdx.x;
    int tn64 = TN << 6;
    int node, c4, slot;
    if (i < tn64) {
        node = i >> 6;
        c4 = i & 63;
        slot = node;
    } else {
        int j = i - tn64;
        if (j >= (TN << 5)) return;
        node = j >> 5;
        c4 = 64 + (j & 31);
        slot = TN + node;
    }
    int start = offs[slot];
    int deg = cnt[slot];
    int end = start + deg;
    float4 acc = make_float4(0.f, 0.f, 0.f, 0.f);
    int k = start;
    // unroll x2: two independent x4 loads in flight per lane
    for (; k + 1 < end; k += 2) {
        int e0 = list[k];
        int e1 = list[k + 1];
        float4 v0 = x4[e0 * C4PER + c4];
        float4 v1 = x4[e1 * C4PER + c4];
        acc.x += v0.x + v1.x;
        acc.y += v0.y + v1.y;
        acc.z += v0.z + v1.z;
        acc.w += v0.w + v1.w;
    }
    if (k < end) {
        int e0 = list[k];
        float4 v0 = x4[e0 * C4PER + c4];
        acc.x += v0.x; acc.y += v0.y; acc.z += v0.z; acc.w += v0.w;
    }
    float inv = 1.0f / (float)max(deg, 1);
    acc.x *= inv; acc.y *= inv; acc.z *= inv; acc.w *= inv;
    out4[node * C4PER + c4] = acc;
}

extern "C" void kernel_launch(void* const* d_in, const int* in_sizes, int n_in,
                              void* d_out, int out_size, void* d_ws, size_t ws_size,
                              hipStream_t stream) {
    const float* x = (const float*)d_in[0];
    const int* org = (const int*)d_in[1];
    const int* ptr = (const int*)d_in[2];
    const int* lg  = (const int*)d_in[3];

    int B  = in_sizes[1];       // 16
    int E  = in_sizes[3] / 2;   // 320000
    int TN = out_size / DIM;    // 160000 total nodes
    int n2 = 2 * TN;

    // ws layout (ints): cnt[2*TN] | offs[2*TN] | bsum[1024] | list[2*E] | rk[2*E]
    int* cnt  = (int*)d_ws;
    int* offs = cnt + n2;
    int* bsum = offs + n2;
    int* list = bsum + 1024;
    int2* rk  = (int2*)(list + 2 * E);   // byte offset divisible by 8

    hipMemsetAsync(cnt, 0, (size_t)n2 * sizeof(int), stream);

    count_kernel<<<(E + 255) / 256, 256, 0, stream>>>(org, ptr, (const int2*)lg, B, E, TN,
                                                      cnt, rk);

    int nb = (n2 + SCAN_CHUNK - 1) / SCAN_CHUNK;
    scan1_kernel<<<nb, SCAN_BLOCK, 0, stream>>>(cnt, offs, bsum, n2);
    scan2_kernel<<<1, SCAN_BLOCK, 0, stream>>>(bsum, nb);
    scan3_kernel<<<(n2 + 255) / 256, 256, 0, stream>>>(offs, bsum, n2);

    fill_kernel<<<(E + 255) / 256, 256, 0, stream>>>(org, ptr, (const int2*)lg, rk, offs,
                                                     B, E, TN, list);

    int total = TN * C4PER;  // 15.36M output float4s
    gather_kernel<<<(total + 255) / 256, 256, 0, stream>>>((const float4*)x, cnt, offs, list,
                                                           (float4*)d_out, TN);
}

// Round 2
// 753.144 us; speedup vs baseline: 1.0659x; 1.0088x over previous
//
#include <hip/hip_runtime.h>

#define DIM 384
#define C4PER 96    // 384/4 float4s per row
// cols [0,256) = incoming mean (keyed by lg[2e+1]) -> 64 float4s
// cols [256,384) = outgoing mean (keyed by lg[2e]) -> 32 float4s

#define SCAN_BLOCK 256
#define SCAN_ITEMS 8
#define SCAN_CHUNK (SCAN_BLOCK * SCAN_ITEMS)  // 2048; slot>>11 picks the chunk

// Per-edge: resolve global node ids, bump degree counts, RECORD RANKS.
// cnt[0..TN)   = in-degree  (keyed by lg[2e+1]+off) -> serves cols [0,256)
// cnt[TN..2TN) = out-degree (keyed by lg[2e]+off)   -> serves cols [256,384)
__global__ void count_kernel(const int* __restrict__ org, const int* __restrict__ ptr,
                             const int2* __restrict__ lg2, int B, int E, int TN,
                             int* __restrict__ cnt, int2* __restrict__ rk) {
    int e = blockIdx.x * blockDim.x + threadIdx.x;
    if (e >= E) return;
    int off = 0;
#pragma unroll 8
    for (int j = 0; j < B; ++j)
        if (e >= ptr[j + 1]) off += org[j];   // uniform addrs -> broadcast loads
    int2 nn = lg2[e];                          // (n_out, n_in)
    int r_in  = atomicAdd(&cnt[nn.y + off], 1);
    int r_out = atomicAdd(&cnt[TN + nn.x + off], 1);
    rk[e] = make_int2(r_out, r_in);
}

// Scan stage 1: per-2048-chunk partial exclusive scan.
// Writes pair[i] = (partial_prefix_within_chunk, count_i) and bsum[chunk].
// Final segment start = pair[i].x + scanned_bsum[i>>11]  (scan3 eliminated).
__global__ void scan1_kernel(const int* __restrict__ cnt, int2* __restrict__ pair,
                             int* __restrict__ bsum, int n) {
    __shared__ int s[SCAN_BLOCK];
    int base = blockIdx.x * SCAN_CHUNK;
    int tid = threadIdx.x;
    int v[SCAN_ITEMS];
    int tsum = 0;
#pragma unroll
    for (int j = 0; j < SCAN_ITEMS; ++j) {
        int i = base + tid * SCAN_ITEMS + j;
        v[j] = (i < n) ? cnt[i] : 0;
        tsum += v[j];
    }
    s[tid] = tsum;
    __syncthreads();
    for (int d = 1; d < SCAN_BLOCK; d <<= 1) {
        int t = (tid >= d) ? s[tid - d] : 0;
        __syncthreads();
        s[tid] += t;
        __syncthreads();
    }
    if (tid == SCAN_BLOCK - 1) bsum[blockIdx.x] = s[SCAN_BLOCK - 1];
    int run = (tid > 0) ? s[tid - 1] : 0;
#pragma unroll
    for (int j = 0; j < SCAN_ITEMS; ++j) {
        int i = base + tid * SCAN_ITEMS + j;
        if (i < n) pair[i] = make_int2(run, v[j]);
        run += v[j];
    }
}

// Stage 2: exclusive scan of block sums in place (single block).
__global__ void scan2_kernel(int* __restrict__ bsum, int nb) {
    __shared__ int s[SCAN_BLOCK];
    int tid = threadIdx.x;
    int carry = 0;
    for (int base = 0; base < nb; base += SCAN_BLOCK) {
        int i = base + tid;
        s[tid] = (i < nb) ? bsum[i] : 0;
        __syncthreads();
        for (int d = 1; d < SCAN_BLOCK; d <<= 1) {
            int t = (tid >= d) ? s[tid - d] : 0;
            __syncthreads();
            s[tid] += t;
            __syncthreads();
        }
        int excl = carry + ((tid > 0) ? s[tid - 1] : 0);
        if (i < nb) bsum[i] = excl;
        carry += s[SCAN_BLOCK - 1];
        __syncthreads();
    }
}

// Fill CSR edge lists using precomputed ranks — no atomics.
__global__ void fill_kernel(const int* __restrict__ org, const int* __restrict__ ptr,
                            const int2* __restrict__ lg2, const int2* __restrict__ rk,
                            const int2* __restrict__ pair, const int* __restrict__ bsum,
                            int B, int E, int TN, int* __restrict__ list) {
    int e = blockIdx.x * blockDim.x + threadIdx.x;
    if (e >= E) return;
    int off = 0;
#pragma unroll 8
    for (int j = 0; j < B; ++j)
        if (e >= ptr[j + 1]) off += org[j];
    int2 nn = lg2[e];
    int2 r  = rk[e];
    int s_in  = nn.y + off;
    int s_out = TN + nn.x + off;
    list[pair[s_in].x  + bsum[s_in  >> 11] + r.y] = e;
    list[pair[s_out].x + bsum[s_out >> 11] + r.x] = e;
}

// Segment gather with lane-parallel list fetch + shfl broadcast:
// the whole edge list for a segment is fetched in ONE coalesced load,
// then x4 loads issue 4-deep with no list->x dependent chain.
template <int W>
__device__ inline float4 gather_seg(const float4* __restrict__ x4,
                                    const int* __restrict__ list,
                                    int start, int deg, int c4, int sub) {
    int e_l = (sub < deg) ? list[start + sub] : 0;
    float4 acc = make_float4(0.f, 0.f, 0.f, 0.f);
    int kf = (deg < W) ? deg : W;
    int k = 0;
    for (; k + 4 <= kf; k += 4) {
        int e0 = __shfl(e_l, k,     W);
        int e1 = __shfl(e_l, k + 1, W);
        int e2 = __shfl(e_l, k + 2, W);
        int e3 = __shfl(e_l, k + 3, W);
        float4 v0 = x4[(size_t)e0 * C4PER + c4];
        float4 v1 = x4[(size_t)e1 * C4PER + c4];
        float4 v2 = x4[(size_t)e2 * C4PER + c4];
        float4 v3 = x4[(size_t)e3 * C4PER + c4];
        acc.x += (v0.x + v1.x) + (v2.x + v3.x);
        acc.y += (v0.y + v1.y) + (v2.y + v3.y);
        acc.z += (v0.z + v1.z) + (v2.z + v3.z);
        acc.w += (v0.w + v1.w) + (v2.w + v3.w);
    }
    for (; k < kf; ++k) {
        int e0 = __shfl(e_l, k, W);
        float4 v = x4[(size_t)e0 * C4PER + c4];
        acc.x += v.x; acc.y += v.y; acc.z += v.z; acc.w += v.w;
    }
    for (; k < deg; ++k) {        // deg > W fallback (vanishingly rare)
        int e0 = list[start + k];
        float4 v = x4[(size_t)e0 * C4PER + c4];
        acc.x += v.x; acc.y += v.y; acc.z += v.z; acc.w += v.w;
    }
    return acc;
}

// Gather-mean, divergence-free wave mapping:
//   threads [0, TN*64): in-half, node = i>>6, c4 = i&63 -> one wave == one node.
//   threads [TN*64, TN*96): out-half, node = j>>5, c4 = 64+(j&31) -> 2 nodes/wave.
// TN*64 is a multiple of 256, so no wave mixes halves.
__global__ __launch_bounds__(256, 8)
void gather_kernel(const float4* __restrict__ x4,
                   const int2* __restrict__ pair, const int* __restrict__ bsum,
                   const int* __restrict__ list,
                   float4* __restrict__ out4, int TN) {
    int i = blockIdx.x * blockDim.x + threadIdx.x;
    int lane = threadIdx.x & 63;
    int tn64 = TN << 6;
    float4 acc;
    int node, c4, deg;
    if (i < tn64) {
        node = i >> 6;
        c4 = i & 63;
        int slot = node;
        int2 pr = pair[slot];                    // one 8B broadcast load
        int start = pr.x + bsum[slot >> 11];     // bsum: ~600B, L1-hot
        deg = pr.y;
        acc = gather_seg<64>(x4, list, start, deg, c4, lane);
    } else {
        int j = i - tn64;
        if (j >= (TN << 5)) return;
        node = j >> 5;
        c4 = 64 + (j & 31);
        int slot = TN + node;
        int2 pr = pair[slot];
        int start = pr.x + bsum[slot >> 11];
        deg = pr.y;
        acc = gather_seg<32>(x4, list, start, deg, c4, lane & 31);
    }
    float inv = 1.0f / (float)max(deg, 1);
    acc.x *= inv; acc.y *= inv; acc.z *= inv; acc.w *= inv;
    out4[(size_t)node * C4PER + c4] = acc;
}

extern "C" void kernel_launch(void* const* d_in, const int* in_sizes, int n_in,
                              void* d_out, int out_size, void* d_ws, size_t ws_size,
                              hipStream_t stream) {
    const float* x = (const float*)d_in[0];
    const int* org = (const int*)d_in[1];
    const int* ptr = (const int*)d_in[2];
    const int* lg  = (const int*)d_in[3];

    int B  = in_sizes[1];       // 16
    int E  = in_sizes[3] / 2;   // 320000
    int TN = out_size / DIM;    // 160000 total nodes
    int n2 = 2 * TN;

    // ws layout (ints): cnt[n2] | pair[int2 x n2] | bsum[1024] | list[2E] | rk[int2 x E]
    int* cnt   = (int*)d_ws;
    int2* pair = (int2*)(cnt + n2);          // n2 ints in -> 8B aligned
    int* bsum  = (int*)(pair + n2);
    int* list  = bsum + 1024;
    int2* rk   = (int2*)(list + 2 * E);      // byte offset divisible by 8

    hipMemsetAsync(cnt, 0, (size_t)n2 * sizeof(int), stream);

    count_kernel<<<(E + 255) / 256, 256, 0, stream>>>(org, ptr, (const int2*)lg, B, E, TN,
                                                      cnt, rk);

    int nb = (n2 + SCAN_CHUNK - 1) / SCAN_CHUNK;
    scan1_kernel<<<nb, SCAN_BLOCK, 0, stream>>>(cnt, pair, bsum, n2);
    scan2_kernel<<<1, SCAN_BLOCK, 0, stream>>>(bsum, nb);

    fill_kernel<<<(E + 255) / 256, 256, 0, stream>>>(org, ptr, (const int2*)lg, rk, pair,
                                                     bsum, B, E, TN, list);

    int total = TN * C4PER;  // 15.36M output float4s
    gather_kernel<<<(total + 255) / 256, 256, 0, stream>>>((const float4*)x, pair, bsum,
                                                           list, (float4*)d_out, TN);
}